// Round 5
// baseline (432.384 us; speedup 1.0000x reference)
//
#include <hip/hip_runtime.h>
#include <hip/hip_bf16.h>
#include <stdint.h>

// TermEncoder GAT: N=50000, E=800000, D=128, H=2, C=128, HC=256
// R9:  full fp16 pipeline, 435.4 us.
// R13: max-free softmax (VALUBusy 51->43, dur flat -> NOT VALU-bound),
//      multi-block scan restored. 432.2 us.
// R14 (this round):
//  - agg: force MLP. VGPR=24 proved compiler kept <=2 gathers in flight
//    (the per-pair `if (jj<n)` guard blocks load batching). s=0 for tail
//    lanes means addresses are ALWAYS valid -> drop the guard (w=0 makes
//    tail FMAs no-ops) and batch explicitly: 8x shuffle -> 8x load into
//    regs -> 8x FMA. Discriminates latency-bound (agg -> ~47us) vs
//    L3-BW-bound (agg flat -> it's at the random-gather floor).
//  - scan2: 1-thread 49-iter serial loop -> one-wave shuffle scan.
#define HC 256
#define NEG_SLOPE 0.2f
#define SOFTMAX_EPS 1e-16f

typedef float floatx4 __attribute__((ext_vector_type(4)));
typedef _Float16 half8v __attribute__((ext_vector_type(8)));

__device__ __forceinline__ float in_load(const void* p, int i, int is_bf16) {
    return is_bf16 ? (float)((const __bf16*)p)[i] : ((const float*)p)[i];
}

// ---------------------------------------------------------------------------
// Fused preprocessing: per-block dtype sniff (ballot over x's first 64 words)
// + all conversions in one launch.
// ---------------------------------------------------------------------------
__global__ void prep_kernel(
    const void* __restrict__ xin, _Float16* __restrict__ x16, int nx,
    const void* __restrict__ w1,  _Float16* __restrict__ W1f, int n1,
    const void* __restrict__ w2,  _Float16* __restrict__ W2f, int n2,
    const void* __restrict__ wp1, _Float16* __restrict__ Wp1f, int n3,
    const void* __restrict__ wp2, _Float16* __restrict__ Wp2f, int n4,
    const void* __restrict__ a0, float* __restrict__ o0, int m0,
    const void* __restrict__ a1, float* __restrict__ o1, int m1,
    const void* __restrict__ a2, float* __restrict__ o2, int m2,
    const void* __restrict__ a3, float* __restrict__ o3, int m3,
    const void* __restrict__ a4, float* __restrict__ o4, int m4,
    const void* __restrict__ a5, float* __restrict__ o5, int m5) {
    // wave-uniform bf16 detection (same 64 words for every wave -> consistent)
    const uint32_t w = ((const uint32_t*)xin)[threadIdx.x & 63];
    const uint32_t ef = ((w & 0xFFFFu) >> 7) & 0xFFu;
    const int fb = (__popcll(__ballot(ef >= 90u && ef <= 135u)) > 48) ? 1 : 0;

    int off = blockIdx.x * blockDim.x + threadIdx.x;
    if (off < nx) { x16[off] = (_Float16)in_load(xin, off, fb); return; }
    off -= nx;
    if (off < n1) { W1f[off] = (_Float16)in_load(w1, off, fb); return; }
    off -= n1;
    if (off < n2) { W2f[off] = (_Float16)in_load(w2, off, fb); return; }
    off -= n2;
    if (off < n3) { Wp1f[off] = (_Float16)in_load(wp1, off, fb); return; }
    off -= n3;
    if (off < n4) { Wp2f[off] = (_Float16)in_load(wp2, off, fb); return; }
    off -= n4;
    if (off < m0) { o0[off] = in_load(a0, off, fb); return; }
    off -= m0;
    if (off < m1) { o1[off] = in_load(a1, off, fb); return; }
    off -= m1;
    if (off < m2) { o2[off] = in_load(a2, off, fb); return; }
    off -= m2;
    if (off < m3) { o3[off] = in_load(a3, off, fb); return; }
    off -= m3;
    if (off < m4) { o4[off] = in_load(a4, off, fb); return; }
    off -= m4;
    if (off < m5) { o5[off] = in_load(a5, off, fb); return; }
}

// ---------------------------------------------------------------------------
// GEMM: C[M,O] = A[M,KTEMP]@B[O,KTEMP]^T (+bias), fp16 operands, f32 acc.
// Block = 256 thr = 4 waves, M-tile 64; wave w owns O/4 cols (TW tiles).
// ALPHA (OTILES==16): fused per-row per-head att dots (f32).
// OMODE: 0=f32 out, 2=fp16 out.  (unchanged this round)
// ---------------------------------------------------------------------------
template <int KTEMP, int OTILES, bool BIAS, bool ALPHA, int OMODE>
__global__ __launch_bounds__(256, 2) void gemm_bt(
    const _Float16* __restrict__ A, const _Float16* __restrict__ B,
    const float* __restrict__ bias,
    float* __restrict__ C, _Float16* __restrict__ Cf16,
    const float* __restrict__ attl, const float* __restrict__ attr,
    float* __restrict__ al, float* __restrict__ ar,
    int M) {
    static_assert(!ALPHA || OTILES == 16, "alpha fusion assumes O=256");
    constexpr int TW = OTILES / 4;
    constexpr int O = OTILES * 16;
    const int tid = threadIdx.x;
    const int lane = tid & 63;
    const int wave = tid >> 6;
    const int mbase = blockIdx.x * 64;
    const int l15 = lane & 15;
    const int q = lane >> 4;
    const int kq = q * 8;
    const int wc = wave * TW * 16;

    int arow[4];
#pragma unroll
    for (int rt = 0; rt < 4; rt++) arow[rt] = min(mbase + rt * 16 + l15, M - 1);

    floatx4 acc[4][TW];
#pragma unroll
    for (int rt = 0; rt < 4; rt++)
#pragma unroll
        for (int tt = 0; tt < TW; tt++) acc[rt][tt] = (floatx4){0.f, 0.f, 0.f, 0.f};

    constexpr int KSTEPS = KTEMP / 32;
#pragma unroll
    for (int ks = 0; ks < KSTEPS; ks++) {
        const int k0 = ks * 32;
        half8v af[4], bf[TW];
#pragma unroll
        for (int rt = 0; rt < 4; rt++)
            af[rt] = *(const half8v*)(A + (size_t)arow[rt] * KTEMP + k0 + kq);
#pragma unroll
        for (int tt = 0; tt < TW; tt++)
            bf[tt] = *(const half8v*)(B + (size_t)(wc + tt * 16 + l15) * KTEMP + k0 + kq);
#pragma unroll
        for (int rt = 0; rt < 4; rt++)
#pragma unroll
            for (int tt = 0; tt < TW; tt++)
                acc[rt][tt] = __builtin_amdgcn_mfma_f32_16x16x32_f16(af[rt], bf[tt], acc[rt][tt], 0, 0, 0);
    }

    // C/D layout: col = lane&15, row(in tile) = q*4 + reg  [m89/m91; dtype-indep]
    float aLp[4][4], aRp[4][4];
    if constexpr (ALPHA) {
#pragma unroll
        for (int rt = 0; rt < 4; rt++)
#pragma unroll
            for (int r = 0; r < 4; r++) { aLp[rt][r] = 0.f; aRp[rt][r] = 0.f; }
    }

#pragma unroll
    for (int rt = 0; rt < 4; rt++) {
        const int rb = mbase + rt * 16 + q * 4;
#pragma unroll
        for (int tt = 0; tt < TW; tt++) {
            const int gcol = wc + tt * 16 + l15;
            float atlv = 0.f, atrv = 0.f;
            if constexpr (ALPHA) { atlv = attl[gcol]; atrv = attr[gcol]; }
#pragma unroll
            for (int r = 0; r < 4; r++) {
                float v = acc[rt][tt][r];
                if constexpr (BIAS) v += bias[gcol];
                if constexpr (ALPHA) { aLp[rt][r] += v * atlv; aRp[rt][r] += v * atrv; }
                const int grow = rb + r;
                if (grow < M) {
                    if constexpr (OMODE == 2) {
                        Cf16[(size_t)grow * O + gcol] = (_Float16)v;
                    } else {
                        C[(size_t)grow * O + gcol] = v;
                    }
                }
            }
        }
    }

    if constexpr (ALPHA) {
        __shared__ float sAL[4][64], sAR[4][64];
#pragma unroll
        for (int rt = 0; rt < 4; rt++)
#pragma unroll
            for (int r = 0; r < 4; r++) {
                float vl = aLp[rt][r], vr = aRp[rt][r];
                vl += __shfl_xor(vl, 1); vl += __shfl_xor(vl, 2);
                vl += __shfl_xor(vl, 4); vl += __shfl_xor(vl, 8);
                vr += __shfl_xor(vr, 1); vr += __shfl_xor(vr, 2);
                vr += __shfl_xor(vr, 4); vr += __shfl_xor(vr, 8);
                if (l15 == 0) {
                    sAL[wave][rt * 16 + q * 4 + r] = vl;
                    sAR[wave][rt * 16 + q * 4 + r] = vr;
                }
            }
        __syncthreads();
        if (tid < 64) {
            const int grow = mbase + tid;
            if (grow < M) {
                al[2 * grow]     = sAL[0][tid] + sAL[1][tid];   // head 0 = waves 0,1
                al[2 * grow + 1] = sAL[2][tid] + sAL[3][tid];   // head 1 = waves 2,3
                ar[2 * grow]     = sAR[0][tid] + sAR[1][tid];
                ar[2 * grow + 1] = sAR[2][tid] + sAR[3][tid];
            }
        }
    }
}

// ---------------------------------------------------------------------------
// CSR build (int64 sniff inlined per-wave: ballot over first 64 odd words)
// ---------------------------------------------------------------------------
__device__ __forceinline__ int edge_is64(const int* ei) {
    const uint32_t* ew = (const uint32_t*)ei;
    uint32_t myw = ew[2 * (threadIdx.x & 63) + 1];
    return (__ballot(myw != 0u) == 0ull) ? 1 : 0;
}
__device__ __forceinline__ int edge_src(const int* ei, int E, int e, int is64) {
    return is64 ? ei[2 * (size_t)e] : ei[e];
}
__device__ __forceinline__ int edge_dst(const int* ei, int E, int e, int is64) {
    return is64 ? ei[2 * (size_t)E + 2 * (size_t)e] : ei[(size_t)E + e];
}

__global__ void count_kernel(const int* __restrict__ ei, int E,
                             int* __restrict__ counts) {
    const int is64 = edge_is64(ei);
    int e = blockIdx.x * blockDim.x + threadIdx.x;
    if (e < E) atomicAdd(&counts[edge_dst(ei, E, e, is64)], 1);
}

// multi-block parallel scan
__global__ __launch_bounds__(1024) void scan1_kernel(const int* __restrict__ counts,
                                                     int* __restrict__ incl,
                                                     int* __restrict__ bsum, int N) {
    __shared__ int tmp[1024];
    const int t = threadIdx.x;
    const int i = blockIdx.x * 1024 + t;
    int v = (i < N) ? counts[i] : 0;
    tmp[t] = v;
    __syncthreads();
    for (int off = 1; off < 1024; off <<= 1) {
        int x = (t >= off) ? tmp[t - off] : 0;
        __syncthreads();
        tmp[t] += x;
        __syncthreads();
    }
    if (i < N) incl[i] = tmp[t];
    if (t == 1023) bsum[blockIdx.x] = tmp[1023];
}

// R14: one-wave shuffle scan over block sums (nb=49 <= 64 lanes); replaces
// the 1-thread serial loop (pure-latency dispatch).
__global__ void scan2_kernel(const int* __restrict__ bsum, int* __restrict__ boffs,
                             int nb, int* __restrict__ row_ptr, int N) {
    const int lane = threadIdx.x & 63;
    const int v = (lane < nb) ? bsum[lane] : 0;
    int inc = v;
#pragma unroll
    for (int off = 1; off < 64; off <<= 1) {
        int y = __shfl_up(inc, off);
        if (lane >= off) inc += y;
    }
    if (lane < nb) boffs[lane] = inc - v;
    if (lane == 63) row_ptr[N] = inc;
}

__global__ void scan3_kernel(const int* __restrict__ incl, const int* __restrict__ counts,
                             const int* __restrict__ boffs, int* __restrict__ row_ptr,
                             int* __restrict__ fill, int N) {
    int i = blockIdx.x * blockDim.x + threadIdx.x;
    if (i < N) {
        int v = boffs[i >> 10] + incl[i] - counts[i];
        row_ptr[i] = v;
        fill[i] = v;
    }
}

__global__ void scatter_kernel(const int* __restrict__ ei, int E,
                               int* __restrict__ fill, int* __restrict__ esrc) {
    const int is64 = edge_is64(ei);
    int e = blockIdx.x * blockDim.x + threadIdx.x;
    if (e < E) {
        int s = edge_src(ei, E, e, is64);
        int d = edge_dst(ei, E, e, is64);
        int pos = atomicAdd(&fill[d], 1);
        esrc[pos] = s;
    }
}

// ---------------------------------------------------------------------------
// Fused segment softmax + aggregation, wave-per-node, max-free softmax.
// R14: unconditional gathers (s=0 tail lanes -> valid addr, w=0 -> FMA no-op)
// + explicit batch-of-8: 8 shuffles -> 8 loads in flight -> 8 FMA blocks.
// ---------------------------------------------------------------------------
__global__ __launch_bounds__(256) void agg_fused_kernel(
    const _Float16* __restrict__ xl,
    const float* __restrict__ al, const float* __restrict__ ar,
    const int* __restrict__ row_ptr, const int* __restrict__ esrc,
    _Float16* __restrict__ hout, int N) {
    const int wid = (blockIdx.x * 256 + threadIdx.x) >> 6;   // node id
    if (wid >= N) return;
    const int lane = threadIdx.x & 63;
    const int half = lane >> 5;          // which edge of the pair
    const int c8 = (lane & 31) * 8;      // my 8-column base
    const int hsel = c8 >> 7;            // head of my columns
    const int hshift = hsel << 4;        // 0 or 16: fp16 half select
    const int s0 = row_ptr[wid], e0 = row_ptr[wid + 1];
    const float ar0 = ar[2 * wid], ar1 = ar[2 * wid + 1];

    float acc[8];
#pragma unroll
    for (int c = 0; c < 8; c++) acc[c] = 0.f;
    float l0 = 0.f, l1 = 0.f;

    for (int base = s0; base < e0; base += 64) {
        const int n = min(64, e0 - base);
        int s = 0;
        float p0 = 0.f, p1 = 0.f;
        if (lane < n) {
            s = esrc[base + lane];
            float2 av = *(const float2*)(al + 2 * s);
            float lg0 = av.x + ar0; lg0 = lg0 > 0.f ? lg0 : NEG_SLOPE * lg0;
            float lg1 = av.y + ar1; lg1 = lg1 > 0.f ? lg1 : NEG_SLOPE * lg1;
            p0 = __expf(__builtin_fminf(lg0, 10.f));
            p1 = __expf(__builtin_fminf(lg1, 10.f));
        }
        // quantize once; quantized p used for BOTH numerator and denominator
        auto pk2 = __builtin_amdgcn_cvt_pkrtz(p0, p1);   // __fp16 ext_vector(2)
        const uint32_t pku = __builtin_bit_cast(uint32_t, pk2);
        l0 += (float)pk2[0];
        l1 += (float)pk2[1];

        // full batches of 8 pair-iterations (16 edges): forced 8-deep MLP
        int j0 = 0;
        for (; j0 + 16 <= n; j0 += 16) {
            uint32_t wu[8];
            int ssu[8];
#pragma unroll
            for (int u = 0; u < 8; u++) {
                const int jj = j0 + 2 * u + half;
                wu[u] = (uint32_t)__shfl((int)pku, jj);
                ssu[u] = __shfl(s, jj);
            }
            half8v xv[8];
#pragma unroll
            for (int u = 0; u < 8; u++)
                xv[u] = *(const half8v*)(xl + (size_t)ssu[u] * HC + c8);
#pragma unroll
            for (int u = 0; u < 8; u++) {
                const unsigned short wb = (unsigned short)(wu[u] >> hshift);
                const float wf = (float)__builtin_bit_cast(_Float16, wb);
#pragma unroll
                for (int c = 0; c < 8; c++) acc[c] += wf * (float)xv[u][c];
            }
        }
        // tail pairs (unconditional: tail lanes hold s=0/w=0)
        for (; j0 < n; j0 += 2) {
            const int jj = j0 + half;
            const uint32_t w32 = (uint32_t)__shfl((int)pku, jj);
            const int ss = __shfl(s, jj);
            const unsigned short wb = (unsigned short)(w32 >> hshift);
            const float wf = (float)__builtin_bit_cast(_Float16, wb);
            half8v xv = *(const half8v*)(xl + (size_t)ss * HC + c8);
#pragma unroll
            for (int c = 0; c < 8; c++) acc[c] += wf * (float)xv[c];
        }
    }

#pragma unroll
    for (int off = 1; off < 64; off <<= 1) {
        l0 += __shfl_xor(l0, off);
        l1 += __shfl_xor(l1, off);
    }
    const float winv = 1.f / ((hsel ? l1 : l0) + SOFTMAX_EPS);

#pragma unroll
    for (int c = 0; c < 8; c++) {
        acc[c] += __shfl_xor(acc[c], 32);
        acc[c] = fmaxf(acc[c] * winv, 0.f);   // fused relu
    }
    if (half == 0) {
        half8v vo;
#pragma unroll
        for (int c = 0; c < 8; c++) vo[c] = (_Float16)acc[c];
        *(half8v*)(hout + (size_t)wid * HC + c8) = vo;
    }
}

// ---------------------------------------------------------------------------
extern "C" void kernel_launch(void* const* d_in, const int* in_sizes, int n_in,
                              void* d_out, int out_size, void* d_ws, size_t ws_size,
                              hipStream_t stream) {
    const int D = 128;
    const int N = in_sizes[0] / D;   // 50000
    const int E = in_sizes[1] / 2;   // 800000
    const int* ei = (const int*)d_in[1];

    char* w = (char*)d_ws;
    auto alloc = [&](size_t bytes) {
        void* p = w;
        w += (bytes + 255) & ~(size_t)255;
        return p;
    };
    _Float16* x16    = (_Float16*)alloc((size_t)N * D * 2);      // x; reused as p
    _Float16* W1f    = (_Float16*)alloc((size_t)in_sizes[2] * 2);
    _Float16* W2f    = (_Float16*)alloc((size_t)in_sizes[5] * 2);
    _Float16* Wp1f   = (_Float16*)alloc((size_t)in_sizes[8] * 2);
    _Float16* Wp2f   = (_Float16*)alloc((size_t)in_sizes[10] * 2);
    float*    atl1   = (float*)   alloc((size_t)in_sizes[3] * 4);
    float*    atr1   = (float*)   alloc((size_t)in_sizes[4] * 4);
    float*    atl2   = (float*)   alloc((size_t)in_sizes[6] * 4);
    float*    atr2   = (float*)   alloc((size_t)in_sizes[7] * 4);
    float*    bfp1   = (float*)   alloc((size_t)in_sizes[9] * 4);
    float*    bfp2   = (float*)   alloc((size_t)in_sizes[11] * 4);
    _Float16* xl16   = (_Float16*)alloc((size_t)N * HC * 2);     // 25.6 MB
    _Float16* h16    = (_Float16*)alloc((size_t)N * HC * 2);     // 25.6 MB
    float*    al     = (float*)   alloc((size_t)N * 2 * 4);
    float*    ar     = (float*)   alloc((size_t)N * 2 * 4);
    int*      counts = (int*)     alloc((size_t)N * 4);
    int*      incl   = (int*)     alloc((size_t)N * 4);
    int*      row_ptr= (int*)     alloc((size_t)(N + 1) * 4);
    int*      fill   = (int*)     alloc((size_t)N * 4);
    int*      bsum   = (int*)     alloc(1024);
    int*      boffs  = (int*)     alloc(1024);
    int*      esrc   = (int*)     alloc((size_t)E * 4);

    const int EB = (E + 255) / 256;
    const int GM = (N + 63) / 64;
    const int NB1024 = (N + 1023) / 1024;
    const int AGG_B = (N + 3) / 4;   // wave per node, 4 waves/block

    // 0. fused dtype sniff + canonicalize (fp16 operands, f32 att/bias)
    {
        int ntot = in_sizes[0] + in_sizes[2] + in_sizes[5] + in_sizes[8] + in_sizes[10]
                 + in_sizes[3] + in_sizes[4] + in_sizes[6] + in_sizes[7]
                 + in_sizes[9] + in_sizes[11];
        prep_kernel<<<(ntot + 255) / 256, 256, 0, stream>>>(
            d_in[0], x16, in_sizes[0],
            d_in[2], W1f, in_sizes[2],
            d_in[5], W2f, in_sizes[5],
            d_in[8], Wp1f, in_sizes[8],
            d_in[10], Wp2f, in_sizes[10],
            d_in[3], atl1, in_sizes[3],
            d_in[4], atr1, in_sizes[4],
            d_in[6], atl2, in_sizes[6],
            d_in[7], atr2, in_sizes[7],
            d_in[9], bfp1, in_sizes[9],
            d_in[11], bfp2, in_sizes[11]);
    }

    // 1. CSR build
    (void)hipMemsetAsync(counts, 0, (size_t)N * 4, stream);
    count_kernel<<<EB, 256, 0, stream>>>(ei, E, counts);
    scan1_kernel<<<NB1024, 1024, 0, stream>>>(counts, incl, bsum, N);
    scan2_kernel<<<1, 64, 0, stream>>>(bsum, boffs, NB1024, row_ptr, N);
    scan3_kernel<<<(N + 255) / 256, 256, 0, stream>>>(incl, counts, boffs, row_ptr, fill, N);
    scatter_kernel<<<EB, 256, 0, stream>>>(ei, E, fill, esrc);

    // 2. GAT layer 1: xl16 = x@W1^T (alpha fused), K=128
    gemm_bt<128, 16, false, true, 2><<<GM, 256, 0, stream>>>(
        x16, W1f, nullptr, nullptr, xl16, atl1, atr1, al, ar, N);
    agg_fused_kernel<<<AGG_B, 256, 0, stream>>>(xl16, al, ar, row_ptr, esrc, h16, N);

    // 3. GAT layer 2: xl16 = h1@W2^T (alpha fused), K=256
    gemm_bt<256, 16, false, true, 2><<<GM, 256, 0, stream>>>(
        h16, W2f, nullptr, nullptr, xl16, atl2, atr2, al, ar, N);
    agg_fused_kernel<<<AGG_B, 256, 0, stream>>>(xl16, al, ar, row_ptr, esrc, h16, N);

    // 4. projections: p = h2@Wp1^T + bp1 (K=256, O=128, fp16 out into x16)
    gemm_bt<256, 8, true, false, 2><<<GM, 256, 0, stream>>>(
        h16, Wp1f, bfp1, nullptr, x16, nullptr, nullptr, nullptr, nullptr, N);
    // out = p@Wp2^T + bp2 (K=128, O=128) -> f32 d_out
    gemm_bt<128, 8, true, false, 0><<<GM, 256, 0, stream>>>(
        x16, Wp2f, bfp2, (float*)d_out, nullptr, nullptr, nullptr, nullptr, nullptr, N);
}

// Round 6
// 422.064 us; speedup vs baseline: 1.0245x; 1.0245x over previous
//
#include <hip/hip_runtime.h>
#include <hip/hip_bf16.h>
#include <stdint.h>

// TermEncoder GAT: N=50000, E=800000, D=128, H=2, C=128, HC=256
// R13: max-free softmax, 432.2 us. agg VALU-theories refuted twice.
// R14: batched gathers (VGPR 24->48) -> agg FLAT at 62.7, FETCH unchanged
//      => agg is at the L2-miss-path floor (~210MB @ ~3.4TB/s). Reverted
//      the batch loop (kept simpler R13 body).
// R15 (this round):
//  - VISIBILITY: agg split into 2 half-node dispatches per layer (~31us
//    each) so the largest non-agg kernel surfaces in top-5 with counters.
//    (2x62us agg = only 29% of total; ~150us is unattributed.)
//  - proj GEMM3+GEMM4 fused: p-tile lives in XOR-swizzled LDS (2-way
//    conflict-free b128 reads), kills the 25.6MB p round-trip + 1 dispatch.
//  - count_kernel merged into prep_kernel (block-range split).
#define HC 256
#define NEG_SLOPE 0.2f
#define SOFTMAX_EPS 1e-16f

typedef float floatx4 __attribute__((ext_vector_type(4)));
typedef _Float16 half8v __attribute__((ext_vector_type(8)));

__device__ __forceinline__ float in_load(const void* p, int i, int is_bf16) {
    return is_bf16 ? (float)((const __bf16*)p)[i] : ((const float*)p)[i];
}

// ---------------------------------------------------------------------------
// CSR helpers (int64 sniff per-wave: ballot over first 64 odd words)
// ---------------------------------------------------------------------------
__device__ __forceinline__ int edge_is64(const int* ei) {
    const uint32_t* ew = (const uint32_t*)ei;
    uint32_t myw = ew[2 * (threadIdx.x & 63) + 1];
    return (__ballot(myw != 0u) == 0ull) ? 1 : 0;
}
__device__ __forceinline__ int edge_src(const int* ei, int E, int e, int is64) {
    return is64 ? ei[2 * (size_t)e] : ei[e];
}
__device__ __forceinline__ int edge_dst(const int* ei, int E, int e, int is64) {
    return is64 ? ei[2 * (size_t)E + 2 * (size_t)e] : ei[(size_t)E + e];
}

// ---------------------------------------------------------------------------
// Fused preprocessing + degree count. Blocks [0, prep_blocks) convert dtypes
// (per-block ballot sniff on x's first 64 words); blocks >= prep_blocks do
// the destination-degree count (independent work, overlaps conversion).
// ---------------------------------------------------------------------------
__global__ void prep_count_kernel(
    const void* __restrict__ xin, _Float16* __restrict__ x16, int nx,
    const void* __restrict__ w1,  _Float16* __restrict__ W1f, int n1,
    const void* __restrict__ w2,  _Float16* __restrict__ W2f, int n2,
    const void* __restrict__ wp1, _Float16* __restrict__ Wp1f, int n3,
    const void* __restrict__ wp2, _Float16* __restrict__ Wp2f, int n4,
    const void* __restrict__ a0, float* __restrict__ o0, int m0,
    const void* __restrict__ a1, float* __restrict__ o1, int m1,
    const void* __restrict__ a2, float* __restrict__ o2, int m2,
    const void* __restrict__ a3, float* __restrict__ o3, int m3,
    const void* __restrict__ a4, float* __restrict__ o4, int m4,
    const void* __restrict__ a5, float* __restrict__ o5, int m5,
    const int* __restrict__ ei, int E, int* __restrict__ counts,
    int prep_blocks) {
    if (blockIdx.x >= prep_blocks) {
        const int is64 = edge_is64(ei);
        int e = (blockIdx.x - prep_blocks) * blockDim.x + threadIdx.x;
        if (e < E) atomicAdd(&counts[edge_dst(ei, E, e, is64)], 1);
        return;
    }
    // wave-uniform bf16 detection (same 64 words for every wave -> consistent)
    const uint32_t w = ((const uint32_t*)xin)[threadIdx.x & 63];
    const uint32_t ef = ((w & 0xFFFFu) >> 7) & 0xFFu;
    const int fb = (__popcll(__ballot(ef >= 90u && ef <= 135u)) > 48) ? 1 : 0;

    int off = blockIdx.x * blockDim.x + threadIdx.x;
    if (off < nx) { x16[off] = (_Float16)in_load(xin, off, fb); return; }
    off -= nx;
    if (off < n1) { W1f[off] = (_Float16)in_load(w1, off, fb); return; }
    off -= n1;
    if (off < n2) { W2f[off] = (_Float16)in_load(w2, off, fb); return; }
    off -= n2;
    if (off < n3) { Wp1f[off] = (_Float16)in_load(wp1, off, fb); return; }
    off -= n3;
    if (off < n4) { Wp2f[off] = (_Float16)in_load(wp2, off, fb); return; }
    off -= n4;
    if (off < m0) { o0[off] = in_load(a0, off, fb); return; }
    off -= m0;
    if (off < m1) { o1[off] = in_load(a1, off, fb); return; }
    off -= m1;
    if (off < m2) { o2[off] = in_load(a2, off, fb); return; }
    off -= m2;
    if (off < m3) { o3[off] = in_load(a3, off, fb); return; }
    off -= m3;
    if (off < m4) { o4[off] = in_load(a4, off, fb); return; }
    off -= m4;
    if (off < m5) { o5[off] = in_load(a5, off, fb); return; }
}

// ---------------------------------------------------------------------------
// GEMM: C[M,O] = A[M,KTEMP]@B[O,KTEMP]^T (+bias), fp16 operands, f32 acc.
// Block = 256 thr = 4 waves, M-tile 64; wave w owns O/4 cols (TW tiles).
// ALPHA (OTILES==16): fused per-row per-head att dots (f32).
// OMODE: 0=f32 out, 2=fp16 out.
// ---------------------------------------------------------------------------
template <int KTEMP, int OTILES, bool BIAS, bool ALPHA, int OMODE>
__global__ __launch_bounds__(256, 2) void gemm_bt(
    const _Float16* __restrict__ A, const _Float16* __restrict__ B,
    const float* __restrict__ bias,
    float* __restrict__ C, _Float16* __restrict__ Cf16,
    const float* __restrict__ attl, const float* __restrict__ attr,
    float* __restrict__ al, float* __restrict__ ar,
    int M) {
    static_assert(!ALPHA || OTILES == 16, "alpha fusion assumes O=256");
    constexpr int TW = OTILES / 4;
    constexpr int O = OTILES * 16;
    const int tid = threadIdx.x;
    const int lane = tid & 63;
    const int wave = tid >> 6;
    const int mbase = blockIdx.x * 64;
    const int l15 = lane & 15;
    const int q = lane >> 4;
    const int kq = q * 8;
    const int wc = wave * TW * 16;

    int arow[4];
#pragma unroll
    for (int rt = 0; rt < 4; rt++) arow[rt] = min(mbase + rt * 16 + l15, M - 1);

    floatx4 acc[4][TW];
#pragma unroll
    for (int rt = 0; rt < 4; rt++)
#pragma unroll
        for (int tt = 0; tt < TW; tt++) acc[rt][tt] = (floatx4){0.f, 0.f, 0.f, 0.f};

    constexpr int KSTEPS = KTEMP / 32;
#pragma unroll
    for (int ks = 0; ks < KSTEPS; ks++) {
        const int k0 = ks * 32;
        half8v af[4], bf[TW];
#pragma unroll
        for (int rt = 0; rt < 4; rt++)
            af[rt] = *(const half8v*)(A + (size_t)arow[rt] * KTEMP + k0 + kq);
#pragma unroll
        for (int tt = 0; tt < TW; tt++)
            bf[tt] = *(const half8v*)(B + (size_t)(wc + tt * 16 + l15) * KTEMP + k0 + kq);
#pragma unroll
        for (int rt = 0; rt < 4; rt++)
#pragma unroll
            for (int tt = 0; tt < TW; tt++)
                acc[rt][tt] = __builtin_amdgcn_mfma_f32_16x16x32_f16(af[rt], bf[tt], acc[rt][tt], 0, 0, 0);
    }

    // C/D layout: col = lane&15, row(in tile) = q*4 + reg  [m89/m91; dtype-indep]
    float aLp[4][4], aRp[4][4];
    if constexpr (ALPHA) {
#pragma unroll
        for (int rt = 0; rt < 4; rt++)
#pragma unroll
            for (int r = 0; r < 4; r++) { aLp[rt][r] = 0.f; aRp[rt][r] = 0.f; }
    }

#pragma unroll
    for (int rt = 0; rt < 4; rt++) {
        const int rb = mbase + rt * 16 + q * 4;
#pragma unroll
        for (int tt = 0; tt < TW; tt++) {
            const int gcol = wc + tt * 16 + l15;
            float atlv = 0.f, atrv = 0.f;
            if constexpr (ALPHA) { atlv = attl[gcol]; atrv = attr[gcol]; }
#pragma unroll
            for (int r = 0; r < 4; r++) {
                float v = acc[rt][tt][r];
                if constexpr (BIAS) v += bias[gcol];
                if constexpr (ALPHA) { aLp[rt][r] += v * atlv; aRp[rt][r] += v * atrv; }
                const int grow = rb + r;
                if (grow < M) {
                    if constexpr (OMODE == 2) {
                        Cf16[(size_t)grow * O + gcol] = (_Float16)v;
                    } else {
                        C[(size_t)grow * O + gcol] = v;
                    }
                }
            }
        }
    }

    if constexpr (ALPHA) {
        __shared__ float sAL[4][64], sAR[4][64];
#pragma unroll
        for (int rt = 0; rt < 4; rt++)
#pragma unroll
            for (int r = 0; r < 4; r++) {
                float vl = aLp[rt][r], vr = aRp[rt][r];
                vl += __shfl_xor(vl, 1); vl += __shfl_xor(vl, 2);
                vl += __shfl_xor(vl, 4); vl += __shfl_xor(vl, 8);
                vr += __shfl_xor(vr, 1); vr += __shfl_xor(vr, 2);
                vr += __shfl_xor(vr, 4); vr += __shfl_xor(vr, 8);
                if (l15 == 0) {
                    sAL[wave][rt * 16 + q * 4 + r] = vl;
                    sAR[wave][rt * 16 + q * 4 + r] = vr;
                }
            }
        __syncthreads();
        if (tid < 64) {
            const int grow = mbase + tid;
            if (grow < M) {
                al[2 * grow]     = sAL[0][tid] + sAL[1][tid];   // head 0 = waves 0,1
                al[2 * grow + 1] = sAL[2][tid] + sAL[3][tid];   // head 1 = waves 2,3
                ar[2 * grow]     = sAR[0][tid] + sAR[1][tid];
                ar[2 * grow + 1] = sAR[2][tid] + sAR[3][tid];
            }
        }
    }
}

// ---------------------------------------------------------------------------
// Fused projection: out = (h2@Wp1^T + bp1)@Wp2^T + bp2.  K1=256,O1=128,
// K2=128,O2=128. p-tile (64x128 fp16) lives in LDS with XOR swizzle:
// byte(row,col) = row*256 + (((col>>3) ^ (row&15))<<4) + (col&7)*2
// -> phase-2 b128 reads are 2-way (free); bijective per row.
// ---------------------------------------------------------------------------
__global__ __launch_bounds__(256, 2) void proj_fused_kernel(
    const _Float16* __restrict__ A, const _Float16* __restrict__ B1,
    const float* __restrict__ b1, const _Float16* __restrict__ B2,
    const float* __restrict__ b2, float* __restrict__ out, int M) {
    __shared__ _Float16 plds[64 * 128];
    const int tid = threadIdx.x;
    const int lane = tid & 63;
    const int wave = tid >> 6;
    const int mbase = blockIdx.x * 64;
    const int l15 = lane & 15;
    const int q = lane >> 4;
    const int kq = q * 8;
    const int wc = wave * 32;   // 2 tiles of 16 cols per wave (O=128)

    int arow[4];
#pragma unroll
    for (int rt = 0; rt < 4; rt++) arow[rt] = min(mbase + rt * 16 + l15, M - 1);

    // phase 1: p = A@B1^T + b1   (K=256)
    floatx4 acc[4][2];
#pragma unroll
    for (int rt = 0; rt < 4; rt++)
#pragma unroll
        for (int tt = 0; tt < 2; tt++) acc[rt][tt] = (floatx4){0.f, 0.f, 0.f, 0.f};
#pragma unroll
    for (int ks = 0; ks < 8; ks++) {
        const int k0 = ks * 32;
        half8v af[4], bf[2];
#pragma unroll
        for (int rt = 0; rt < 4; rt++)
            af[rt] = *(const half8v*)(A + (size_t)arow[rt] * 256 + k0 + kq);
#pragma unroll
        for (int tt = 0; tt < 2; tt++)
            bf[tt] = *(const half8v*)(B1 + (size_t)(wc + tt * 16 + l15) * 256 + k0 + kq);
#pragma unroll
        for (int rt = 0; rt < 4; rt++)
#pragma unroll
            for (int tt = 0; tt < 2; tt++)
                acc[rt][tt] = __builtin_amdgcn_mfma_f32_16x16x32_f16(af[rt], bf[tt], acc[rt][tt], 0, 0, 0);
    }
    // epilogue -> swizzled LDS (fp16, bias added: identical numerics to the
    // old fp16 p intermediate)
#pragma unroll
    for (int rt = 0; rt < 4; rt++) {
#pragma unroll
        for (int tt = 0; tt < 2; tt++) {
            const int col = wc + tt * 16 + l15;
            const float bv = b1[col];
#pragma unroll
            for (int r = 0; r < 4; r++) {
                const int row = rt * 16 + q * 4 + r;
                const int byt = row * 256 + ((((col >> 3) ^ (row & 15)) << 4)) + (col & 7) * 2;
                *(_Float16*)((char*)plds + byt) = (_Float16)(acc[rt][tt][r] + bv);
            }
        }
    }
    __syncthreads();

    // phase 2: out = p@B2^T + b2   (K=128)
    floatx4 acc2[4][2];
#pragma unroll
    for (int rt = 0; rt < 4; rt++)
#pragma unroll
        for (int tt = 0; tt < 2; tt++) acc2[rt][tt] = (floatx4){0.f, 0.f, 0.f, 0.f};
#pragma unroll
    for (int ks = 0; ks < 4; ks++) {
        half8v af[4], bf[2];
#pragma unroll
        for (int rt = 0; rt < 4; rt++) {
            const int row = rt * 16 + l15;
            // chunk index = ks*4 + q; swizzle with row&15 = l15
            const int byt = (row << 8) + (((ks * 4 + q) ^ l15) << 4);
            af[rt] = *(const half8v*)((const char*)plds + byt);
        }
#pragma unroll
        for (int tt = 0; tt < 2; tt++)
            bf[tt] = *(const half8v*)(B2 + (size_t)(wc + tt * 16 + l15) * 128 + ks * 32 + kq);
#pragma unroll
        for (int rt = 0; rt < 4; rt++)
#pragma unroll
            for (int tt = 0; tt < 2; tt++)
                acc2[rt][tt] = __builtin_amdgcn_mfma_f32_16x16x32_f16(af[rt], bf[tt], acc2[rt][tt], 0, 0, 0);
    }
#pragma unroll
    for (int rt = 0; rt < 4; rt++) {
        const int rb = mbase + rt * 16 + q * 4;
#pragma unroll
        for (int tt = 0; tt < 2; tt++) {
            const int gcol = wc + tt * 16 + l15;
            const float bv = b2[gcol];
#pragma unroll
            for (int r = 0; r < 4; r++) {
                const int grow = rb + r;
                if (grow < M) out[(size_t)grow * 128 + gcol] = acc2[rt][tt][r] + bv;
            }
        }
    }
}

// ---------------------------------------------------------------------------
// CSR scan + scatter (multi-block parallel scan)
// ---------------------------------------------------------------------------
__global__ __launch_bounds__(1024) void scan1_kernel(const int* __restrict__ counts,
                                                     int* __restrict__ incl,
                                                     int* __restrict__ bsum, int N) {
    __shared__ int tmp[1024];
    const int t = threadIdx.x;
    const int i = blockIdx.x * 1024 + t;
    int v = (i < N) ? counts[i] : 0;
    tmp[t] = v;
    __syncthreads();
    for (int off = 1; off < 1024; off <<= 1) {
        int x = (t >= off) ? tmp[t - off] : 0;
        __syncthreads();
        tmp[t] += x;
        __syncthreads();
    }
    if (i < N) incl[i] = tmp[t];
    if (t == 1023) bsum[blockIdx.x] = tmp[1023];
}

// one-wave shuffle scan over block sums (nb=49 <= 64 lanes)
__global__ void scan2_kernel(const int* __restrict__ bsum, int* __restrict__ boffs,
                             int nb, int* __restrict__ row_ptr, int N) {
    const int lane = threadIdx.x & 63;
    const int v = (lane < nb) ? bsum[lane] : 0;
    int inc = v;
#pragma unroll
    for (int off = 1; off < 64; off <<= 1) {
        int y = __shfl_up(inc, off);
        if (lane >= off) inc += y;
    }
    if (lane < nb) boffs[lane] = inc - v;
    if (lane == 63) row_ptr[N] = inc;
}

__global__ void scan3_kernel(const int* __restrict__ incl, const int* __restrict__ counts,
                             const int* __restrict__ boffs, int* __restrict__ row_ptr,
                             int* __restrict__ fill, int N) {
    int i = blockIdx.x * blockDim.x + threadIdx.x;
    if (i < N) {
        int v = boffs[i >> 10] + incl[i] - counts[i];
        row_ptr[i] = v;
        fill[i] = v;
    }
}

__global__ void scatter_kernel(const int* __restrict__ ei, int E,
                               int* __restrict__ fill, int* __restrict__ esrc) {
    const int is64 = edge_is64(ei);
    int e = blockIdx.x * blockDim.x + threadIdx.x;
    if (e < E) {
        int s = edge_src(ei, E, e, is64);
        int d = edge_dst(ei, E, e, is64);
        int pos = atomicAdd(&fill[d], 1);
        esrc[pos] = s;
    }
}

// ---------------------------------------------------------------------------
// Fused segment softmax + aggregation, wave-per-node, max-free softmax
// (R13 body — R14 batching was measured neutral). R15: node-range split for
// profiler visibility (each dispatch handles [nlo, nhi)).
// ---------------------------------------------------------------------------
__global__ __launch_bounds__(256) void agg_fused_kernel(
    const _Float16* __restrict__ xl,
    const float* __restrict__ al, const float* __restrict__ ar,
    const int* __restrict__ row_ptr, const int* __restrict__ esrc,
    _Float16* __restrict__ hout, int nlo, int nhi) {
    const int wid = nlo + ((blockIdx.x * 256 + threadIdx.x) >> 6);   // node id
    if (wid >= nhi) return;
    const int lane = threadIdx.x & 63;
    const int half = lane >> 5;          // which edge of the pair
    const int c8 = (lane & 31) * 8;      // my 8-column base
    const int hsel = c8 >> 7;            // head of my columns
    const int hshift = hsel << 4;        // 0 or 16: fp16 half select
    const int s0 = row_ptr[wid], e0 = row_ptr[wid + 1];
    const float ar0 = ar[2 * wid], ar1 = ar[2 * wid + 1];

    float acc[8];
#pragma unroll
    for (int c = 0; c < 8; c++) acc[c] = 0.f;
    float l0 = 0.f, l1 = 0.f;

    for (int base = s0; base < e0; base += 64) {
        const int n = min(64, e0 - base);
        int s = 0;
        float p0 = 0.f, p1 = 0.f;
        if (lane < n) {
            s = esrc[base + lane];
            float2 av = *(const float2*)(al + 2 * s);
            float lg0 = av.x + ar0; lg0 = lg0 > 0.f ? lg0 : NEG_SLOPE * lg0;
            float lg1 = av.y + ar1; lg1 = lg1 > 0.f ? lg1 : NEG_SLOPE * lg1;
            p0 = __expf(__builtin_fminf(lg0, 10.f));
            p1 = __expf(__builtin_fminf(lg1, 10.f));
        }
        // quantize once; quantized p used for BOTH numerator and denominator
        auto pk2 = __builtin_amdgcn_cvt_pkrtz(p0, p1);   // __fp16 ext_vector(2)
        const uint32_t pku = __builtin_bit_cast(uint32_t, pk2);
        l0 += (float)pk2[0];
        l1 += (float)pk2[1];

#pragma unroll 8
        for (int j = 0; j < n; j += 2) {
            const int jj = j + half;
            const uint32_t w32 = (uint32_t)__shfl((int)pku, jj);
            const int ss = __shfl(s, jj);
            const unsigned short wb = (unsigned short)(w32 >> hshift);
            const float wf = (float)__builtin_bit_cast(_Float16, wb);
            half8v xv = *(const half8v*)(xl + (size_t)ss * HC + c8);
#pragma unroll
            for (int c = 0; c < 8; c++) acc[c] += wf * (float)xv[c];
        }
    }

#pragma unroll
    for (int off = 1; off < 64; off <<= 1) {
        l0 += __shfl_xor(l0, off);
        l1 += __shfl_xor(l1, off);
    }
    const float winv = 1.f / ((hsel ? l1 : l0) + SOFTMAX_EPS);

#pragma unroll
    for (int c = 0; c < 8; c++) {
        acc[c] += __shfl_xor(acc[c], 32);
        acc[c] = fmaxf(acc[c] * winv, 0.f);   // fused relu
    }
    if (half == 0) {
        half8v vo;
#pragma unroll
        for (int c = 0; c < 8; c++) vo[c] = (_Float16)acc[c];
        *(half8v*)(hout + (size_t)wid * HC + c8) = vo;
    }
}

// ---------------------------------------------------------------------------
extern "C" void kernel_launch(void* const* d_in, const int* in_sizes, int n_in,
                              void* d_out, int out_size, void* d_ws, size_t ws_size,
                              hipStream_t stream) {
    const int D = 128;
    const int N = in_sizes[0] / D;   // 50000
    const int E = in_sizes[1] / 2;   // 800000
    const int* ei = (const int*)d_in[1];

    char* w = (char*)d_ws;
    auto alloc = [&](size_t bytes) {
        void* p = w;
        w += (bytes + 255) & ~(size_t)255;
        return p;
    };
    _Float16* x16    = (_Float16*)alloc((size_t)N * D * 2);
    _Float16* W1f    = (_Float16*)alloc((size_t)in_sizes[2] * 2);
    _Float16* W2f    = (_Float16*)alloc((size_t)in_sizes[5] * 2);
    _Float16* Wp1f   = (_Float16*)alloc((size_t)in_sizes[8] * 2);
    _Float16* Wp2f   = (_Float16*)alloc((size_t)in_sizes[10] * 2);
    float*    atl1   = (float*)   alloc((size_t)in_sizes[3] * 4);
    float*    atr1   = (float*)   alloc((size_t)in_sizes[4] * 4);
    float*    atl2   = (float*)   alloc((size_t)in_sizes[6] * 4);
    float*    atr2   = (float*)   alloc((size_t)in_sizes[7] * 4);
    float*    bfp1   = (float*)   alloc((size_t)in_sizes[9] * 4);
    float*    bfp2   = (float*)   alloc((size_t)in_sizes[11] * 4);
    _Float16* xl16   = (_Float16*)alloc((size_t)N * HC * 2);     // 25.6 MB
    _Float16* h16    = (_Float16*)alloc((size_t)N * HC * 2);     // 25.6 MB
    float*    al     = (float*)   alloc((size_t)N * 2 * 4);
    float*    ar     = (float*)   alloc((size_t)N * 2 * 4);
    int*      counts = (int*)     alloc((size_t)N * 4);
    int*      incl   = (int*)     alloc((size_t)N * 4);
    int*      row_ptr= (int*)     alloc((size_t)(N + 1) * 4);
    int*      fill   = (int*)     alloc((size_t)N * 4);
    int*      bsum   = (int*)     alloc(1024);
    int*      boffs  = (int*)     alloc(1024);
    int*      esrc   = (int*)     alloc((size_t)E * 4);

    const int EB = (E + 255) / 256;
    const int GM = (N + 63) / 64;
    const int NB1024 = (N + 1023) / 1024;
    const int NH = N / 2;                       // 25000
    const int AGG_B1 = (NH + 3) / 4;
    const int AGG_B2 = (N - NH + 3) / 4;

    // 0. memset + fused dtype-sniff/convert/count
    (void)hipMemsetAsync(counts, 0, (size_t)N * 4, stream);
    {
        int ntot = in_sizes[0] + in_sizes[2] + in_sizes[5] + in_sizes[8] + in_sizes[10]
                 + in_sizes[3] + in_sizes[4] + in_sizes[6] + in_sizes[7]
                 + in_sizes[9] + in_sizes[11];
        int prep_blocks = (ntot + 255) / 256;
        prep_count_kernel<<<prep_blocks + EB, 256, 0, stream>>>(
            d_in[0], x16, in_sizes[0],
            d_in[2], W1f, in_sizes[2],
            d_in[5], W2f, in_sizes[5],
            d_in[8], Wp1f, in_sizes[8],
            d_in[10], Wp2f, in_sizes[10],
            d_in[3], atl1, in_sizes[3],
            d_in[4], atr1, in_sizes[4],
            d_in[6], atl2, in_sizes[6],
            d_in[7], atr2, in_sizes[7],
            d_in[9], bfp1, in_sizes[9],
            d_in[11], bfp2, in_sizes[11],
            ei, E, counts, prep_blocks);
    }

    // 1. CSR scan + scatter
    scan1_kernel<<<NB1024, 1024, 0, stream>>>(counts, incl, bsum, N);
    scan2_kernel<<<1, 64, 0, stream>>>(bsum, boffs, NB1024, row_ptr, N);
    scan3_kernel<<<(N + 255) / 256, 256, 0, stream>>>(incl, counts, boffs, row_ptr, fill, N);
    scatter_kernel<<<EB, 256, 0, stream>>>(ei, E, fill, esrc);

    // 2. GAT layer 1: xl16 = x@W1^T (alpha fused), K=128
    gemm_bt<128, 16, false, true, 2><<<GM, 256, 0, stream>>>(
        x16, W1f, nullptr, nullptr, xl16, atl1, atr1, al, ar, N);
    agg_fused_kernel<<<AGG_B1, 256, 0, stream>>>(xl16, al, ar, row_ptr, esrc, h16, 0, NH);
    agg_fused_kernel<<<AGG_B2, 256, 0, stream>>>(xl16, al, ar, row_ptr, esrc, h16, NH, N);

    // 3. GAT layer 2: xl16 = h1@W2^T (alpha fused), K=256
    gemm_bt<256, 16, false, true, 2><<<GM, 256, 0, stream>>>(
        h16, W2f, nullptr, nullptr, xl16, atl2, atr2, al, ar, N);
    agg_fused_kernel<<<AGG_B1, 256, 0, stream>>>(xl16, al, ar, row_ptr, esrc, h16, 0, NH);
    agg_fused_kernel<<<AGG_B2, 256, 0, stream>>>(xl16, al, ar, row_ptr, esrc, h16, NH, N);

    // 4. fused projections: out = (h2@Wp1^T+bp1)@Wp2^T+bp2
    proj_fused_kernel<<<GM, 256, 0, stream>>>(
        h16, Wp1f, bfp1, Wp2f, bfp2, (float*)d_out, N);
}

// Round 7
// 421.584 us; speedup vs baseline: 1.0256x; 1.0011x over previous
//
#include <hip/hip_runtime.h>
#include <hip/hip_bf16.h>
#include <stdint.h>

// TermEncoder GAT: N=50000, E=800000, D=128, H=2, C=128, HC=256
// R13: max-free softmax, 432.2. R14: batched gathers neutral -> agg at
//      L2-miss floor (~124us total, accepted).
// R15: agg split (visibility), proj fusion, count merge -> 422.1.
//      REVEALED: prep_count ~54us + scatter ~53us, BOTH with VALUBusy<4%,
//      HBM ~12% -> atomic/latency-bound, pipes idle. scatter WRITE 52MB =
//      800k random 4B stores x 64B line writeback (exact).
// R16 (this round): fuse scatter + GEMM1 (independent by dep-graph: scatter
//      needs fill/scan3 only; GEMM1 needs prep only). Scatter blocks first
//      in grid (latency drains under GEMM compute). Predicted fused dispatch
//      ~55-65us, total -> ~390-400.
#define HC 256
#define NEG_SLOPE 0.2f
#define SOFTMAX_EPS 1e-16f

typedef float floatx4 __attribute__((ext_vector_type(4)));
typedef _Float16 half8v __attribute__((ext_vector_type(8)));

__device__ __forceinline__ float in_load(const void* p, int i, int is_bf16) {
    return is_bf16 ? (float)((const __bf16*)p)[i] : ((const float*)p)[i];
}

// ---------------------------------------------------------------------------
// CSR helpers (int64 sniff per-wave: ballot over first 64 odd words)
// ---------------------------------------------------------------------------
__device__ __forceinline__ int edge_is64(const int* ei) {
    const uint32_t* ew = (const uint32_t*)ei;
    uint32_t myw = ew[2 * (threadIdx.x & 63) + 1];
    return (__ballot(myw != 0u) == 0ull) ? 1 : 0;
}
__device__ __forceinline__ int edge_src(const int* ei, int E, int e, int is64) {
    return is64 ? ei[2 * (size_t)e] : ei[e];
}
__device__ __forceinline__ int edge_dst(const int* ei, int E, int e, int is64) {
    return is64 ? ei[2 * (size_t)E + 2 * (size_t)e] : ei[(size_t)E + e];
}

// ---------------------------------------------------------------------------
// Fused preprocessing + degree count (block-range split).
// ---------------------------------------------------------------------------
__global__ void prep_count_kernel(
    const void* __restrict__ xin, _Float16* __restrict__ x16, int nx,
    const void* __restrict__ w1,  _Float16* __restrict__ W1f, int n1,
    const void* __restrict__ w2,  _Float16* __restrict__ W2f, int n2,
    const void* __restrict__ wp1, _Float16* __restrict__ Wp1f, int n3,
    const void* __restrict__ wp2, _Float16* __restrict__ Wp2f, int n4,
    const void* __restrict__ a0, float* __restrict__ o0, int m0,
    const void* __restrict__ a1, float* __restrict__ o1, int m1,
    const void* __restrict__ a2, float* __restrict__ o2, int m2,
    const void* __restrict__ a3, float* __restrict__ o3, int m3,
    const void* __restrict__ a4, float* __restrict__ o4, int m4,
    const void* __restrict__ a5, float* __restrict__ o5, int m5,
    const int* __restrict__ ei, int E, int* __restrict__ counts,
    int prep_blocks) {
    if (blockIdx.x >= prep_blocks) {
        const int is64 = edge_is64(ei);
        int e = (blockIdx.x - prep_blocks) * blockDim.x + threadIdx.x;
        if (e < E) atomicAdd(&counts[edge_dst(ei, E, e, is64)], 1);
        return;
    }
    // wave-uniform bf16 detection (same 64 words for every wave -> consistent)
    const uint32_t w = ((const uint32_t*)xin)[threadIdx.x & 63];
    const uint32_t ef = ((w & 0xFFFFu) >> 7) & 0xFFu;
    const int fb = (__popcll(__ballot(ef >= 90u && ef <= 135u)) > 48) ? 1 : 0;

    int off = blockIdx.x * blockDim.x + threadIdx.x;
    if (off < nx) { x16[off] = (_Float16)in_load(xin, off, fb); return; }
    off -= nx;
    if (off < n1) { W1f[off] = (_Float16)in_load(w1, off, fb); return; }
    off -= n1;
    if (off < n2) { W2f[off] = (_Float16)in_load(w2, off, fb); return; }
    off -= n2;
    if (off < n3) { Wp1f[off] = (_Float16)in_load(wp1, off, fb); return; }
    off -= n3;
    if (off < n4) { Wp2f[off] = (_Float16)in_load(wp2, off, fb); return; }
    off -= n4;
    if (off < m0) { o0[off] = in_load(a0, off, fb); return; }
    off -= m0;
    if (off < m1) { o1[off] = in_load(a1, off, fb); return; }
    off -= m1;
    if (off < m2) { o2[off] = in_load(a2, off, fb); return; }
    off -= m2;
    if (off < m3) { o3[off] = in_load(a3, off, fb); return; }
    off -= m3;
    if (off < m4) { o4[off] = in_load(a4, off, fb); return; }
    off -= m4;
    if (off < m5) { o5[off] = in_load(a5, off, fb); return; }
}

// ---------------------------------------------------------------------------
// GEMM body: C[M,O] = A[M,KTEMP]@B[O,KTEMP]^T (+bias), fp16 ops, f32 acc.
// Device function so it can be fused with other block-ranges (R16).
// ---------------------------------------------------------------------------
template <int KTEMP, int OTILES, bool BIAS, bool ALPHA, int OMODE>
__device__ __forceinline__ void gemm_bt_body(
    int bx,
    const _Float16* __restrict__ A, const _Float16* __restrict__ B,
    const float* __restrict__ bias,
    float* __restrict__ C, _Float16* __restrict__ Cf16,
    const float* __restrict__ attl, const float* __restrict__ attr,
    float* __restrict__ al, float* __restrict__ ar,
    int M) {
    static_assert(!ALPHA || OTILES == 16, "alpha fusion assumes O=256");
    constexpr int TW = OTILES / 4;
    constexpr int O = OTILES * 16;
    const int tid = threadIdx.x;
    const int lane = tid & 63;
    const int wave = tid >> 6;
    const int mbase = bx * 64;
    const int l15 = lane & 15;
    const int q = lane >> 4;
    const int kq = q * 8;
    const int wc = wave * TW * 16;

    int arow[4];
#pragma unroll
    for (int rt = 0; rt < 4; rt++) arow[rt] = min(mbase + rt * 16 + l15, M - 1);

    floatx4 acc[4][TW];
#pragma unroll
    for (int rt = 0; rt < 4; rt++)
#pragma unroll
        for (int tt = 0; tt < TW; tt++) acc[rt][tt] = (floatx4){0.f, 0.f, 0.f, 0.f};

    constexpr int KSTEPS = KTEMP / 32;
#pragma unroll
    for (int ks = 0; ks < KSTEPS; ks++) {
        const int k0 = ks * 32;
        half8v af[4], bf[TW];
#pragma unroll
        for (int rt = 0; rt < 4; rt++)
            af[rt] = *(const half8v*)(A + (size_t)arow[rt] * KTEMP + k0 + kq);
#pragma unroll
        for (int tt = 0; tt < TW; tt++)
            bf[tt] = *(const half8v*)(B + (size_t)(wc + tt * 16 + l15) * KTEMP + k0 + kq);
#pragma unroll
        for (int rt = 0; rt < 4; rt++)
#pragma unroll
            for (int tt = 0; tt < TW; tt++)
                acc[rt][tt] = __builtin_amdgcn_mfma_f32_16x16x32_f16(af[rt], bf[tt], acc[rt][tt], 0, 0, 0);
    }

    // C/D layout: col = lane&15, row(in tile) = q*4 + reg  [m89/m91; dtype-indep]
    float aLp[4][4], aRp[4][4];
    if constexpr (ALPHA) {
#pragma unroll
        for (int rt = 0; rt < 4; rt++)
#pragma unroll
            for (int r = 0; r < 4; r++) { aLp[rt][r] = 0.f; aRp[rt][r] = 0.f; }
    }

#pragma unroll
    for (int rt = 0; rt < 4; rt++) {
        const int rb = mbase + rt * 16 + q * 4;
#pragma unroll
        for (int tt = 0; tt < TW; tt++) {
            const int gcol = wc + tt * 16 + l15;
            float atlv = 0.f, atrv = 0.f;
            if constexpr (ALPHA) { atlv = attl[gcol]; atrv = attr[gcol]; }
#pragma unroll
            for (int r = 0; r < 4; r++) {
                float v = acc[rt][tt][r];
                if constexpr (BIAS) v += bias[gcol];
                if constexpr (ALPHA) { aLp[rt][r] += v * atlv; aRp[rt][r] += v * atrv; }
                const int grow = rb + r;
                if (grow < M) {
                    if constexpr (OMODE == 2) {
                        Cf16[(size_t)grow * O + gcol] = (_Float16)v;
                    } else {
                        C[(size_t)grow * O + gcol] = v;
                    }
                }
            }
        }
    }

    if constexpr (ALPHA) {
        __shared__ float sAL[4][64], sAR[4][64];
#pragma unroll
        for (int rt = 0; rt < 4; rt++)
#pragma unroll
            for (int r = 0; r < 4; r++) {
                float vl = aLp[rt][r], vr = aRp[rt][r];
                vl += __shfl_xor(vl, 1); vl += __shfl_xor(vl, 2);
                vl += __shfl_xor(vl, 4); vl += __shfl_xor(vl, 8);
                vr += __shfl_xor(vr, 1); vr += __shfl_xor(vr, 2);
                vr += __shfl_xor(vr, 4); vr += __shfl_xor(vr, 8);
                if (l15 == 0) {
                    sAL[wave][rt * 16 + q * 4 + r] = vl;
                    sAR[wave][rt * 16 + q * 4 + r] = vr;
                }
            }
        __syncthreads();
        if (tid < 64) {
            const int grow = mbase + tid;
            if (grow < M) {
                al[2 * grow]     = sAL[0][tid] + sAL[1][tid];   // head 0 = waves 0,1
                al[2 * grow + 1] = sAL[2][tid] + sAL[3][tid];   // head 1 = waves 2,3
                ar[2 * grow]     = sAR[0][tid] + sAR[1][tid];
                ar[2 * grow + 1] = sAR[2][tid] + sAR[3][tid];
            }
        }
    }
}

template <int KTEMP, int OTILES, bool BIAS, bool ALPHA, int OMODE>
__global__ __launch_bounds__(256, 2) void gemm_bt(
    const _Float16* __restrict__ A, const _Float16* __restrict__ B,
    const float* __restrict__ bias,
    float* __restrict__ C, _Float16* __restrict__ Cf16,
    const float* __restrict__ attl, const float* __restrict__ attr,
    float* __restrict__ al, float* __restrict__ ar,
    int M) {
    gemm_bt_body<KTEMP, OTILES, BIAS, ALPHA, OMODE>(
        blockIdx.x, A, B, bias, C, Cf16, attl, attr, al, ar, M);
}

// ---------------------------------------------------------------------------
// R16: fused scatter + GEMM1. Scatter blocks FIRST (latency-bound atomics
// start draining immediately); GEMM1 blocks follow and their MFMA/stream
// work fills the idle issue slots (scatter: VALUBusy 0.6%).
// Deps: scatter needs fill (scan3); GEMM1 needs x16/W1f (prep). Independent.
// ---------------------------------------------------------------------------
__global__ __launch_bounds__(256, 2) void gemm1_scatter_kernel(
    const _Float16* __restrict__ A, const _Float16* __restrict__ B,
    _Float16* __restrict__ Cf16,
    const float* __restrict__ attl, const float* __restrict__ attr,
    float* __restrict__ al, float* __restrict__ ar, int M,
    const int* __restrict__ ei, int E,
    int* __restrict__ fill, int* __restrict__ esrc, int scat_blocks) {
    if (blockIdx.x < scat_blocks) {
        const int is64 = edge_is64(ei);
        int e = blockIdx.x * 256 + threadIdx.x;
        if (e < E) {
            int s = edge_src(ei, E, e, is64);
            int d = edge_dst(ei, E, e, is64);
            int pos = atomicAdd(&fill[d], 1);
            esrc[pos] = s;
        }
        return;
    }
    gemm_bt_body<128, 16, false, true, 2>(
        blockIdx.x - scat_blocks, A, B, nullptr, nullptr, Cf16, attl, attr, al, ar, M);
}

// ---------------------------------------------------------------------------
// Fused projection: out = (h2@Wp1^T + bp1)@Wp2^T + bp2.  p-tile in XOR-
// swizzled LDS (2-way conflict-free b128 reads).
// ---------------------------------------------------------------------------
__global__ __launch_bounds__(256, 2) void proj_fused_kernel(
    const _Float16* __restrict__ A, const _Float16* __restrict__ B1,
    const float* __restrict__ b1, const _Float16* __restrict__ B2,
    const float* __restrict__ b2, float* __restrict__ out, int M) {
    __shared__ _Float16 plds[64 * 128];
    const int tid = threadIdx.x;
    const int lane = tid & 63;
    const int wave = tid >> 6;
    const int mbase = blockIdx.x * 64;
    const int l15 = lane & 15;
    const int q = lane >> 4;
    const int kq = q * 8;
    const int wc = wave * 32;   // 2 tiles of 16 cols per wave (O=128)

    int arow[4];
#pragma unroll
    for (int rt = 0; rt < 4; rt++) arow[rt] = min(mbase + rt * 16 + l15, M - 1);

    // phase 1: p = A@B1^T + b1   (K=256)
    floatx4 acc[4][2];
#pragma unroll
    for (int rt = 0; rt < 4; rt++)
#pragma unroll
        for (int tt = 0; tt < 2; tt++) acc[rt][tt] = (floatx4){0.f, 0.f, 0.f, 0.f};
#pragma unroll
    for (int ks = 0; ks < 8; ks++) {
        const int k0 = ks * 32;
        half8v af[4], bf[2];
#pragma unroll
        for (int rt = 0; rt < 4; rt++)
            af[rt] = *(const half8v*)(A + (size_t)arow[rt] * 256 + k0 + kq);
#pragma unroll
        for (int tt = 0; tt < 2; tt++)
            bf[tt] = *(const half8v*)(B1 + (size_t)(wc + tt * 16 + l15) * 256 + k0 + kq);
#pragma unroll
        for (int rt = 0; rt < 4; rt++)
#pragma unroll
            for (int tt = 0; tt < 2; tt++)
                acc[rt][tt] = __builtin_amdgcn_mfma_f32_16x16x32_f16(af[rt], bf[tt], acc[rt][tt], 0, 0, 0);
    }
    // epilogue -> swizzled LDS (fp16, bias added)
#pragma unroll
    for (int rt = 0; rt < 4; rt++) {
#pragma unroll
        for (int tt = 0; tt < 2; tt++) {
            const int col = wc + tt * 16 + l15;
            const float bv = b1[col];
#pragma unroll
            for (int r = 0; r < 4; r++) {
                const int row = rt * 16 + q * 4 + r;
                const int byt = row * 256 + ((((col >> 3) ^ (row & 15)) << 4)) + (col & 7) * 2;
                *(_Float16*)((char*)plds + byt) = (_Float16)(acc[rt][tt][r] + bv);
            }
        }
    }
    __syncthreads();

    // phase 2: out = p@B2^T + b2   (K=128)
    floatx4 acc2[4][2];
#pragma unroll
    for (int rt = 0; rt < 4; rt++)
#pragma unroll
        for (int tt = 0; tt < 2; tt++) acc2[rt][tt] = (floatx4){0.f, 0.f, 0.f, 0.f};
#pragma unroll
    for (int ks = 0; ks < 4; ks++) {
        half8v af[4], bf[2];
#pragma unroll
        for (int rt = 0; rt < 4; rt++) {
            const int row = rt * 16 + l15;
            const int byt = (row << 8) + (((ks * 4 + q) ^ l15) << 4);
            af[rt] = *(const half8v*)((const char*)plds + byt);
        }
#pragma unroll
        for (int tt = 0; tt < 2; tt++)
            bf[tt] = *(const half8v*)(B2 + (size_t)(wc + tt * 16 + l15) * 128 + ks * 32 + kq);
#pragma unroll
        for (int rt = 0; rt < 4; rt++)
#pragma unroll
            for (int tt = 0; tt < 2; tt++)
                acc2[rt][tt] = __builtin_amdgcn_mfma_f32_16x16x32_f16(af[rt], bf[tt], acc2[rt][tt], 0, 0, 0);
    }
#pragma unroll
    for (int rt = 0; rt < 4; rt++) {
        const int rb = mbase + rt * 16 + q * 4;
#pragma unroll
        for (int tt = 0; tt < 2; tt++) {
            const int gcol = wc + tt * 16 + l15;
            const float bv = b2[gcol];
#pragma unroll
            for (int r = 0; r < 4; r++) {
                const int grow = rb + r;
                if (grow < M) out[(size_t)grow * 128 + gcol] = acc2[rt][tt][r] + bv;
            }
        }
    }
}

// ---------------------------------------------------------------------------
// CSR scan (multi-block parallel)
// ---------------------------------------------------------------------------
__global__ __launch_bounds__(1024) void scan1_kernel(const int* __restrict__ counts,
                                                     int* __restrict__ incl,
                                                     int* __restrict__ bsum, int N) {
    __shared__ int tmp[1024];
    const int t = threadIdx.x;
    const int i = blockIdx.x * 1024 + t;
    int v = (i < N) ? counts[i] : 0;
    tmp[t] = v;
    __syncthreads();
    for (int off = 1; off < 1024; off <<= 1) {
        int x = (t >= off) ? tmp[t - off] : 0;
        __syncthreads();
        tmp[t] += x;
        __syncthreads();
    }
    if (i < N) incl[i] = tmp[t];
    if (t == 1023) bsum[blockIdx.x] = tmp[1023];
}

// one-wave shuffle scan over block sums (nb=49 <= 64 lanes)
__global__ void scan2_kernel(const int* __restrict__ bsum, int* __restrict__ boffs,
                             int nb, int* __restrict__ row_ptr, int N) {
    const int lane = threadIdx.x & 63;
    const int v = (lane < nb) ? bsum[lane] : 0;
    int inc = v;
#pragma unroll
    for (int off = 1; off < 64; off <<= 1) {
        int y = __shfl_up(inc, off);
        if (lane >= off) inc += y;
    }
    if (lane < nb) boffs[lane] = inc - v;
    if (lane == 63) row_ptr[N] = inc;
}

__global__ void scan3_kernel(const int* __restrict__ incl, const int* __restrict__ counts,
                             const int* __restrict__ boffs, int* __restrict__ row_ptr,
                             int* __restrict__ fill, int N) {
    int i = blockIdx.x * blockDim.x + threadIdx.x;
    if (i < N) {
        int v = boffs[i >> 10] + incl[i] - counts[i];
        row_ptr[i] = v;
        fill[i] = v;
    }
}

// ---------------------------------------------------------------------------
// Fused segment softmax + aggregation, wave-per-node, max-free softmax.
// Node-range split for profiler visibility.
// ---------------------------------------------------------------------------
__global__ __launch_bounds__(256) void agg_fused_kernel(
    const _Float16* __restrict__ xl,
    const float* __restrict__ al, const float* __restrict__ ar,
    const int* __restrict__ row_ptr, const int* __restrict__ esrc,
    _Float16* __restrict__ hout, int nlo, int nhi) {
    const int wid = nlo + ((blockIdx.x * 256 + threadIdx.x) >> 6);   // node id
    if (wid >= nhi) return;
    const int lane = threadIdx.x & 63;
    const int half = lane >> 5;          // which edge of the pair
    const int c8 = (lane & 31) * 8;      // my 8-column base
    const int hsel = c8 >> 7;            // head of my columns
    const int hshift = hsel << 4;        // 0 or 16: fp16 half select
    const int s0 = row_ptr[wid], e0 = row_ptr[wid + 1];
    const float ar0 = ar[2 * wid], ar1 = ar[2 * wid + 1];

    float acc[8];
#pragma unroll
    for (int c = 0; c < 8; c++) acc[c] = 0.f;
    float l0 = 0.f, l1 = 0.f;

    for (int base = s0; base < e0; base += 64) {
        const int n = min(64, e0 - base);
        int s = 0;
        float p0 = 0.f, p1 = 0.f;
        if (lane < n) {
            s = esrc[base + lane];
            float2 av = *(const float2*)(al + 2 * s);
            float lg0 = av.x + ar0; lg0 = lg0 > 0.f ? lg0 : NEG_SLOPE * lg0;
            float lg1 = av.y + ar1; lg1 = lg1 > 0.f ? lg1 : NEG_SLOPE * lg1;
            p0 = __expf(__builtin_fminf(lg0, 10.f));
            p1 = __expf(__builtin_fminf(lg1, 10.f));
        }
        // quantize once; quantized p used for BOTH numerator and denominator
        auto pk2 = __builtin_amdgcn_cvt_pkrtz(p0, p1);   // __fp16 ext_vector(2)
        const uint32_t pku = __builtin_bit_cast(uint32_t, pk2);
        l0 += (float)pk2[0];
        l1 += (float)pk2[1];

#pragma unroll 8
        for (int j = 0; j < n; j += 2) {
            const int jj = j + half;
            const uint32_t w32 = (uint32_t)__shfl((int)pku, jj);
            const int ss = __shfl(s, jj);
            const unsigned short wb = (unsigned short)(w32 >> hshift);
            const float wf = (float)__builtin_bit_cast(_Float16, wb);
            half8v xv = *(const half8v*)(xl + (size_t)ss * HC + c8);
#pragma unroll
            for (int c = 0; c < 8; c++) acc[c] += wf * (float)xv[c];
        }
    }

#pragma unroll
    for (int off = 1; off < 64; off <<= 1) {
        l0 += __shfl_xor(l0, off);
        l1 += __shfl_xor(l1, off);
    }
    const float winv = 1.f / ((hsel ? l1 : l0) + SOFTMAX_EPS);

#pragma unroll
    for (int c = 0; c < 8; c++) {
        acc[c] += __shfl_xor(acc[c], 32);
        acc[c] = fmaxf(acc[c] * winv, 0.f);   // fused relu
    }
    if (half == 0) {
        half8v vo;
#pragma unroll
        for (int c = 0; c < 8; c++) vo[c] = (_Float16)acc[c];
        *(half8v*)(hout + (size_t)wid * HC + c8) = vo;
    }
}

// ---------------------------------------------------------------------------
extern "C" void kernel_launch(void* const* d_in, const int* in_sizes, int n_in,
                              void* d_out, int out_size, void* d_ws, size_t ws_size,
                              hipStream_t stream) {
    const int D = 128;
    const int N = in_sizes[0] / D;   // 50000
    const int E = in_sizes[1] / 2;   // 800000
    const int* ei = (const int*)d_in[1];

    char* w = (char*)d_ws;
    auto alloc = [&](size_t bytes) {
        void* p = w;
        w += (bytes + 255) & ~(size_t)255;
        return p;
    };
    _Float16* x16    = (_Float16*)alloc((size_t)N * D * 2);
    _Float16* W1f    = (_Float16*)alloc((size_t)in_sizes[2] * 2);
    _Float16* W2f    = (_Float16*)alloc((size_t)in_sizes[5] * 2);
    _Float16* Wp1f   = (_Float16*)alloc((size_t)in_sizes[8] * 2);
    _Float16* Wp2f   = (_Float16*)alloc((size_t)in_sizes[10] * 2);
    float*    atl1   = (float*)   alloc((size_t)in_sizes[3] * 4);
    float*    atr1   = (float*)   alloc((size_t)in_sizes[4] * 4);
    float*    atl2   = (float*)   alloc((size_t)in_sizes[6] * 4);
    float*    atr2   = (float*)   alloc((size_t)in_sizes[7] * 4);
    float*    bfp1   = (float*)   alloc((size_t)in_sizes[9] * 4);
    float*    bfp2   = (float*)   alloc((size_t)in_sizes[11] * 4);
    _Float16* xl16   = (_Float16*)alloc((size_t)N * HC * 2);     // 25.6 MB
    _Float16* h16    = (_Float16*)alloc((size_t)N * HC * 2);     // 25.6 MB
    float*    al     = (float*)   alloc((size_t)N * 2 * 4);
    float*    ar     = (float*)   alloc((size_t)N * 2 * 4);
    int*      counts = (int*)     alloc((size_t)N * 4);
    int*      incl   = (int*)     alloc((size_t)N * 4);
    int*      row_ptr= (int*)     alloc((size_t)(N + 1) * 4);
    int*      fill   = (int*)     alloc((size_t)N * 4);
    int*      bsum   = (int*)     alloc(1024);
    int*      boffs  = (int*)     alloc(1024);
    int*      esrc   = (int*)     alloc((size_t)E * 4);

    const int EB = (E + 255) / 256;
    const int GM = (N + 63) / 64;
    const int NB1024 = (N + 1023) / 1024;
    const int NH = N / 2;                       // 25000
    const int AGG_B1 = (NH + 3) / 4;
    const int AGG_B2 = (N - NH + 3) / 4;

    // 0. memset + fused dtype-sniff/convert/count
    (void)hipMemsetAsync(counts, 0, (size_t)N * 4, stream);
    {
        int ntot = in_sizes[0] + in_sizes[2] + in_sizes[5] + in_sizes[8] + in_sizes[10]
                 + in_sizes[3] + in_sizes[4] + in_sizes[6] + in_sizes[7]
                 + in_sizes[9] + in_sizes[11];
        int prep_blocks = (ntot + 255) / 256;
        prep_count_kernel<<<prep_blocks + EB, 256, 0, stream>>>(
            d_in[0], x16, in_sizes[0],
            d_in[2], W1f, in_sizes[2],
            d_in[5], W2f, in_sizes[5],
            d_in[8], Wp1f, in_sizes[8],
            d_in[10], Wp2f, in_sizes[10],
            d_in[3], atl1, in_sizes[3],
            d_in[4], atr1, in_sizes[4],
            d_in[6], atl2, in_sizes[6],
            d_in[7], atr2, in_sizes[7],
            d_in[9], bfp1, in_sizes[9],
            d_in[11], bfp2, in_sizes[11],
            ei, E, counts, prep_blocks);
    }

    // 1. CSR scan
    scan1_kernel<<<NB1024, 1024, 0, stream>>>(counts, incl, bsum, N);
    scan2_kernel<<<1, 64, 0, stream>>>(bsum, boffs, NB1024, row_ptr, N);
    scan3_kernel<<<(N + 255) / 256, 256, 0, stream>>>(incl, counts, boffs, row_ptr, fill, N);

    // 2. fused: scatter (CSR edge placement) + GAT layer-1 GEMM (independent)
    gemm1_scatter_kernel<<<EB + GM, 256, 0, stream>>>(
        x16, W1f, xl16, atl1, atr1, al, ar, N, ei, E, fill, esrc, EB);

    agg_fused_kernel<<<AGG_B1, 256, 0, stream>>>(xl16, al, ar, row_ptr, esrc, h16, 0, NH);
    agg_fused_kernel<<<AGG_B2, 256, 0, stream>>>(xl16, al, ar, row_ptr, esrc, h16, NH, N);

    // 3. GAT layer 2: xl16 = h1@W2^T (alpha fused), K=256
    gemm_bt<256, 16, false, true, 2><<<GM, 256, 0, stream>>>(
        h16, W2f, nullptr, nullptr, xl16, atl2, atr2, al, ar, N);
    agg_fused_kernel<<<AGG_B1, 256, 0, stream>>>(xl16, al, ar, row_ptr, esrc, h16, 0, NH);
    agg_fused_kernel<<<AGG_B2, 256, 0, stream>>>(xl16, al, ar, row_ptr, esrc, h16, NH, N);

    // 4. fused projections: out = (h2@Wp1^T+bp1)@Wp2^T+bp2
    proj_fused_kernel<<<GM, 256, 0, stream>>>(
        h16, Wp1f, bfp1, Wp2f, bfp2, (float*)d_out, N);
}